// Round 4
// baseline (744.105 us; speedup 1.0000x reference)
//
#include <hip/hip_runtime.h>

// SE block, all fp32: x(64,128,112,112) -> global avg pool -> MLP(128->32->128,
// relu, hard-sigmoid) -> channel-wise scale.
//
// Cohort-pipelined with ORDINARY launches (no cooperative kernel — round 3's
// grid.sync variant hung the container). Stream order is the grid barrier:
//   for each cohort of 16 images (2048 planes = 102 MB):
//       se_pool(cohort)   — reads x once, writes per-plane means s[]
//       se_scale(cohort)  — recomputes the tiny MLP per block (redundant,
//                           ~160 FMAs), re-reads x (L3-resident by
//                           construction: reuse distance <= ~204 MB < 256 MB
//                           Infinity Cache), NT-stores out.
// HBM traffic ideal: 411 MB read + 411 MB write; second read served by L3.

#define C_IN  128
#define C_MID 32
#define HW    12544          // 112*112
#define NVEC4 (HW / 4)       // 3136 float4 per plane
#define PCOH  2048           // planes per cohort = 16 images = 102 MB

typedef float vfloat4 __attribute__((ext_vector_type(4)));

// ---------------- pool: one block per plane ----------------
__global__ __launch_bounds__(256) void se_pool(const float* __restrict__ x,
                                               float* __restrict__ s,
                                               int p0_base) {
    const int plane = p0_base + (int)blockIdx.x;
    const vfloat4* xv = (const vfloat4*)(x + (size_t)plane * HW);
    float acc = 0.0f;
    for (int v = threadIdx.x; v < NVEC4; v += 256) {
        vfloat4 d = xv[v];
        acc += (d.x + d.y) + (d.z + d.w);
    }
    #pragma unroll
    for (int off = 32; off > 0; off >>= 1) acc += __shfl_down(acc, off, 64);
    __shared__ float red[4];
    if ((threadIdx.x & 63) == 0) red[threadIdx.x >> 6] = acc;
    __syncthreads();
    if (threadIdx.x == 0)
        s[plane] = (red[0] + red[1] + red[2] + red[3]) * (1.0f / (float)HW);
}

// ---------- scale + fused excite: one block per plane ----------
__global__ __launch_bounds__(256) void se_scale(const float* __restrict__ x,
                                                const float* __restrict__ s,
                                                const float* __restrict__ w1,
                                                const float* __restrict__ b1,
                                                const float* __restrict__ w2,
                                                const float* __restrict__ b2,
                                                float* __restrict__ out,
                                                int p0_base) {
    const int plane = p0_base + (int)blockIdx.x;
    const int b = plane >> 7;            // plane / C_IN
    const int c = plane & (C_IN - 1);
    const int tid = threadIdx.x;

    // Redundant per-block excite MLP (tiny: weights are 16 KB total, L2-hot).
    __shared__ float sh_s[C_IN];
    __shared__ float sh_h[C_MID];
    if (tid < C_IN) sh_s[tid] = s[b * C_IN + tid];
    __syncthreads();
    if (tid < C_MID) {
        float a = b1[tid];
        #pragma unroll 8
        for (int cc = 0; cc < C_IN; ++cc)
            a += sh_s[cc] * w1[tid * C_IN + cc];   // w1[m][c], (C_MID,C_IN)
        sh_h[tid] = fmaxf(a, 0.0f);
    }
    __syncthreads();
    // Every thread computes the (single, block-uniform) gate redundantly:
    // 32 FMAs off broadcast LDS reads — cheaper than another barrier.
    float a = b2[c];
    #pragma unroll
    for (int m = 0; m < C_MID; ++m)
        a += sh_h[m] * w2[c * C_MID + m];          // w2[c][m], (C_IN,C_MID)
    const float gate = fminf(fmaxf(0.2f * a + 0.5f, 0.0f), 1.0f);

    const vfloat4* xv = (const vfloat4*)(x + (size_t)plane * HW);
    vfloat4* ov = (vfloat4*)(out + (size_t)plane * HW);
    for (int v = tid; v < NVEC4; v += 256) {
        vfloat4 d = xv[v];
        d *= gate;
        // NT store: keep the 411 MB output stream from evicting the cohort's
        // x window before it is re-read.
        __builtin_nontemporal_store(d, &ov[v]);
    }
}

extern "C" void kernel_launch(void* const* d_in, const int* in_sizes, int n_in,
                              void* d_out, int out_size, void* d_ws, size_t ws_size,
                              hipStream_t stream) {
    const float* x  = (const float*)d_in[0];
    const float* w1 = (const float*)d_in[1];
    const float* b1 = (const float*)d_in[2];
    const float* w2 = (const float*)d_in[3];
    const float* b2 = (const float*)d_in[4];
    float* out = (float*)d_out;

    const int planes = in_sizes[0] / HW;   // B * C_IN = 8192
    float* s = (float*)d_ws;               // planes floats (means)

    for (int p0 = 0; p0 < planes; p0 += PCOH) {
        const int np = (planes - p0 < PCOH) ? (planes - p0) : PCOH;
        se_pool <<<np, 256, 0, stream>>>(x, s, p0);
        se_scale<<<np, 256, 0, stream>>>(x, s, w1, b1, w2, b2, out, p0);
    }
}